// Round 4
// baseline (109.472 us; speedup 1.0000x reference)
//
#include <hip/hip_runtime.h>

#define NTY 50
#define NCA 20
#define ED  64
#define NB  4
#define SL  256

#define TYPE_BLOCKS (NB * NTY)   // 200: one per (batch, target type)
#define CAT_BLOCKS  (NB * NCA)   // 80:  one per (batch, target category)
#define MAIN_BLOCKS (TYPE_BLOCKS + CAT_BLOCKS)
#define NTHREADS 512
#define NWAVES   (NTHREADS / 64)
#define JTILE    8

// ws float layout — data slots written via device-scope atomicExch (exact
// overwrite, no zero-init needed); only the completion counter is memset.
#define WS_M   0                        // [NB][SL] per-event type-channel partial
#define WS_N   (NB * SL)                // [NB][SL] per-event cat-channel partial
#define WS_IT  (2 * NB * SL)            // [NB][NTY] horizon type partial
#define WS_NT  (2 * NB * SL + NB * NTY) // [NB][ED] horizon cat n-vector
#define WS_CNT (WS_NT + NB * ED)        // completion counter (1 uint)

__device__ __forceinline__ float softplusf(float x) {
    return (x > 0.f) ? x + log1pf(__expf(-x)) : log1pf(__expf(x));
}

__device__ __forceinline__ float waveReduceSum(float v) {
    #pragma unroll
    for (int off = 32; off > 0; off >>= 1) v += __shfl_down(v, off, 64);
    return v;
}

struct SharedBuf {
    float2 csr_td[SL];          // packed {time, pos-as-float}: 1 ds_read_b64/source
    float  times_sh[SL + 1];    // [SL] = horizon T (virtual event)
    int    types_sh[SL];
    int    cats_sh[SL];
    int    kcnt[NTY];
    int    csr_off[NTY + 1];
    int    evl[SL];
    int    evcnt;
    int    finflag;
    float  trA;
    float  trB[NCA];
    float  qmat[JTILE][NTHREADS];
    float  nmat[NCA][ED];
    float  ftsl[4][ED];         // finisher scratch
    float  fred[4], fi0[4], fintb[4];
};

// Thread owns (k, EPT e-values); W[e] = sum_{matched s<i} exp(R[e]*t_s) in VGPRs.
// CSR per key k -> event loop touches only matched sources; packed b64 CSR +
// register-prefetched event tiles keep the serial LDS chain to ~1 load/step.
template <bool IS_TYPE, int NK, int EPT>
__device__ __forceinline__ void run_channel(
        int b, int tgt, int tid,
        const float* __restrict__ times, const int* __restrict__ types,
        const int* __restrict__ cats, float Tf,
        const float* __restrict__ type_emb, const float* __restrict__ cat_emb,
        const float* __restrict__ amat, const float* __restrict__ bmat,
        const float* __restrict__ Cmat, const float* __restrict__ Pmat,
        float* __restrict__ ws, SharedBuf& sh) {
    const int lane = tid & 63;
    const int w    = tid >> 6;
    constexpr int GPK  = ED / EPT;     // thread-groups per k
    constexpr int NACT = NK * GPK;     // active threads
    const int myk  = tid / GPK;
    const int e0   = (tid % GPK) * EPT;
    const bool active = tid < NACT;
    const int base = b * SL;

    // ---- per-thread coefficient registers (global gathers issued first) ----
    float Rr[EPT], Cr[EPT], W[EPT];
    if (active) {
        #pragma unroll
        for (int m = 0; m < EPT; ++m) {
            const int e = e0 + m;
            const float tr = IS_TYPE ? type_emb[tgt * ED + e] : cat_emb[tgt * ED + e];
            const float f  = IS_TYPE ? type_emb[myk * ED + e] : cat_emb[myk * ED + e];
            Cr[m] = tr * Cmat[(myk * NK + tgt) * ED + e] * f;
            Rr[m] = tr * Pmat[(myk * NK + tgt) * ED + e] * f;
            W[m]  = 0.f;
        }
    }
    float trE = 0.f, aE = 0.f;
    if (IS_TYPE) {
        trE = type_emb[tgt * ED + lane];
        aE  = amat[tgt * ED + lane];
    }

    // ---- stage sequences (split across the 512 threads) ----
    if (tid < SL) {
        sh.times_sh[tid] = times[base + tid];
        sh.types_sh[tid] = types[base + tid];
    } else {
        sh.cats_sh[tid - SL] = cats[base + tid - SL];
    }
    if (tid == 0) sh.times_sh[SL] = Tf;
    __syncthreads();

    const int* keys = IS_TYPE ? sh.types_sh : sh.cats_sh;

    // ---- CSR count (wave w owns k = w mod 8); wave 7 compacts events ----
    for (int k = w; k < NK; k += NWAVES) {
        int cnt = 0;
        #pragma unroll
        for (int c = 0; c < SL / 64; ++c)
            cnt += __popcll(__ballot(keys[lane + 64 * c] == k));
        if (lane == 0) sh.kcnt[k] = cnt;
    }
    if (w == NWAVES - 1) {
        int run = 0;
        #pragma unroll
        for (int c = 0; c < SL / 64; ++c) {
            const int p = lane + 64 * c;
            const bool pred = (p >= 1) && (IS_TYPE ? (sh.types_sh[p] == tgt)
                                                   : (sh.cats_sh[p - 1] == tgt));
            const unsigned long long mk = __ballot(pred);
            if (pred) sh.evl[run + __popcll(mk & ((1ull << lane) - 1ull))] = p;
            run += __popcll(mk);
        }
        if (lane == 0) sh.evcnt = run;
    }
    __syncthreads();

    // ---- offsets scan (wave 0); epilogue scalars trA/trB[c] (other waves) ----
    if (w == 0) {
        int v = (lane < NK) ? sh.kcnt[lane] : 0;
        #pragma unroll
        for (int off = 1; off < 64; off <<= 1) {
            const int u = __shfl_up(v, off, 64);
            if (lane >= off) v += u;
        }
        if (lane < NK) sh.csr_off[lane + 1] = v;
        if (lane == 0) sh.csr_off[0] = 0;
    }
    if (IS_TYPE) {
        if (w == 1) {
            const float r = waveReduceSum(trE * aE);
            if (lane == 0) sh.trA = r;
        }
        for (int c = w; c < NCA; c += NWAVES) {
            const float r = waveReduceSum(trE * bmat[c * ED + lane]);
            if (lane == 0) sh.trB[c] = r;
        }
    }
    __syncthreads();

    // ---- CSR rank-write, packed {time, pos} ----
    for (int k = w; k < NK; k += NWAVES) {
        int bp = sh.csr_off[k];
        #pragma unroll
        for (int c = 0; c < SL / 64; ++c) {
            const int p = lane + 64 * c;
            const bool pr = (keys[p] == k);
            const unsigned long long mk = __ballot(pr);
            if (pr) {
                const int d = bp + __popcll(mk & ((1ull << lane) - 1ull));
                sh.csr_td[d] = make_float2(sh.times_sh[p], __int_as_float(p));
            }
            bp += __popcll(mk);
        }
    }
    __syncthreads();

    const int ne   = sh.evcnt;
    int       m    = active ? sh.csr_off[myk] : 0;
    const int mend = active ? sh.csr_off[myk + 1] : 0;

    for (int j0 = 0; j0 <= ne; j0 += JTILE) {
        const int jhi = min(j0 + JTILE - 1, ne);

        if (active) {
            // ---- register prefetch of the event tile (independent LDS loads) ----
            int iev[JTILE]; float tev[JTILE]; int tEv[JTILE];
            #pragma unroll
            for (int u = 0; u < JTILE; ++u) {
                const int j = j0 + u;
                const int ie = (j < ne) ? sh.evl[j] : SL;
                iev[u] = ie;
                tev[u] = sh.times_sh[ie];
            }
            if (!IS_TYPE) {
                #pragma unroll
                for (int u = 0; u < JTILE; ++u)
                    tEv[u] = (j0 + u < ne) ? sh.types_sh[iev[u]] : 0;
            }
            #pragma unroll
            for (int u = 0; u < JTILE; ++u) {
                const int j = j0 + u;
                if (j > ne) break;
                const int   ie  = iev[u];
                const float tau = tev[u];
                while (m < mend) {
                    const float2 v = sh.csr_td[m];
                    if (__float_as_int(v.y) >= ie) break;
                    #pragma unroll
                    for (int mm = 0; mm < EPT; ++mm) W[mm] += __expf(Rr[mm] * v.x);
                    ++m;
                }
                if (IS_TYPE || j < ne) {
                    float q = 0.f;
                    #pragma unroll
                    for (int mm = 0; mm < EPT; ++mm) {
                        float t1 = Cr[mm] * __expf(-Rr[mm] * tau) * W[mm];
                        if (!IS_TYPE) t1 *= type_emb[tEv[u] * ED + e0 + mm];
                        q += t1;
                    }
                    sh.qmat[u][tid] = q;
                } else {
                    #pragma unroll
                    for (int mm = 0; mm < EPT; ++mm)
                        sh.nmat[myk][e0 + mm] = Cr[mm] * __expf(-Rr[mm] * tau) * W[mm];
                }
            }
        }
        __syncthreads();

        // ---- reduce: one event per wave (JTILE == NWAVES) ----
        {
            const int jj = w;
            const int j = j0 + jj;
            if (jj <= jhi - j0 && !(!IS_TYPE && j == ne)) {
                const int ie = (j < ne) ? sh.evl[j] : SL;
                float p = 0.f;
                #pragma unroll
                for (int m2 = 0; m2 < NWAVES; ++m2) {
                    const int src = lane + 64 * m2;
                    if (src < NACT) p += sh.qmat[jj][src];
                }
                const float r = waveReduceSum(p);
                if (lane == 0) {
                    if (IS_TYPE) {
                        if (j < ne) atomicExch(&ws[WS_M + b * SL + ie],
                                               r + sh.trA + sh.trB[sh.cats_sh[ie - 1]]);
                        else        atomicExch(&ws[WS_IT + b * NTY + tgt], r + sh.trA);
                    } else {
                        atomicExch(&ws[WS_N + b * SL + ie], r);
                    }
                }
            }
        }
        __syncthreads();
    }

    // ---- cat horizon n-vector (only the last_cat block writes) ----
    if (!IS_TYPE && tgt == sh.cats_sh[SL - 1] && w == 0) {
        float nacc = 0.f;
        #pragma unroll
        for (int k = 0; k < NCA; ++k) nacc += sh.nmat[k][lane];
        atomicExch(&ws[WS_NT + b * ED + lane], nacc);
    }
}

__global__ __launch_bounds__(NTHREADS, 4) void hawkes_main(
        const float* __restrict__ times,
        const int*   __restrict__ types,
        const int*   __restrict__ cats,
        const int*   __restrict__ Tp,
        const float* __restrict__ type_emb,
        const float* __restrict__ cat_emb,
        const float* __restrict__ amat,
        const float* __restrict__ bmat,
        const float* __restrict__ A,
        const float* __restrict__ P,
        const float* __restrict__ Bm,
        const float* __restrict__ Q,
        float* __restrict__ ws,
        float* __restrict__ out) {
    const int blk = blockIdx.x;
    const int tid = threadIdx.x;
    __shared__ SharedBuf sh;

    const float Tf = (float)Tp[0];

    if (blk < TYPE_BLOCKS) {
        const int b = blk / NTY, tgt = blk % NTY;
        run_channel<true, NTY, 8>(b, tgt, tid, times, types, cats, Tf,
                                  type_emb, cat_emb, amat, bmat, A, P, ws, sh);
    } else {
        const int cb = blk - TYPE_BLOCKS;
        const int b = cb / NCA, tgt = cb % NCA;
        run_channel<false, NCA, 4>(b, tgt, tid, times, types, cats, Tf,
                                   type_emb, cat_emb, amat, bmat, Bm, Q, ws, sh);
    }

    // ---- completion: last block to arrive runs the finisher (round-0 pattern) ----
    __syncthreads();                        // all this block's atomics drained
    if (tid == 0) {
        sh.finflag = 0;
        __asm__ __volatile__("s_waitcnt vmcnt(0)" ::: "memory");
        const unsigned old = atomicAdd((unsigned int*)&ws[WS_CNT], 1u);
        if (old == MAIN_BLOCKS - 1u) sh.finflag = 1;
    }
    __syncthreads();
    if (!sh.finflag) return;

    // ---- finisher (one block): combine ws via device-scope atomic reads ----
    {
        const int lane = tid & 63;
        const int w    = tid >> 6;
        const int w4   = w & 3;

        float llp = 0.f;
        if (tid < SL - 1) {                 // i = tid+1 in [1, 255]
            const int i = tid + 1;
            #pragma unroll
            for (int bb = 0; bb < NB; ++bb) {
                const float lam = atomicAdd(&ws[WS_M + bb * SL + i], 0.f)
                                + atomicAdd(&ws[WS_N + bb * SL + i], 0.f);
                llp += logf(lam + 1e-16f) + lam;
            }
        }

        float tsp = 0.f, i0p = 0.f, v0 = 0.f;
        if (w < 4) {
            for (int t = w4; t < NTY; t += 4) {
                const float tv = type_emb[t * ED + lane];
                tsp += tv;
                i0p += softplusf(tv * amat[t * ED + lane]);
            }
            sh.ftsl[w4][lane] = tsp;
            const int t0 = types[w4 * SL];
            v0 = softplusf(type_emb[t0 * ED + lane] * amat[t0 * ED + lane]);
        }
        const float wll  = waveReduceSum(llp);
        const float lam0 = waveReduceSum(v0);
        const float wi0  = waveReduceSum(i0p);
        if (w < 4 && lane == 0) {
            sh.fred[w4] = wll + logf(lam0 + 1e-16f) + lam0;
            sh.fi0[w4]  = wi0;
        }
        __syncthreads();

        if (w < 4) {
            const float TS_l = sh.ftsl[0][lane] + sh.ftsl[1][lane]
                             + sh.ftsl[2][lane] + sh.ftsl[3][lane];
            const int   lc  = cats[w4 * SL + SL - 1];
            const float bbv = bmat[lc * ED + lane]
                            + atomicAdd(&ws[WS_NT + w4 * ED + lane], 0.f);
            const float its = (lane < NTY) ? atomicAdd(&ws[WS_IT + w4 * NTY + lane], 0.f) : 0.f;
            const float ip  = waveReduceSum(its + bbv * TS_l);
            if (lane == 0) sh.fintb[w4] = ip * (Tf - times[w4 * SL + SL - 1]);
        }
        __syncthreads();

        if (tid == 0) {
            const float ll  = sh.fred[0] + sh.fred[1] + sh.fred[2] + sh.fred[3];
            const float I0  = sh.fi0[0] + sh.fi0[1] + sh.fi0[2] + sh.fi0[3];
            const float t0s = times[0] + times[SL] + times[2 * SL] + times[3 * SL];
            const float tot = sh.fintb[0] + sh.fintb[1] + sh.fintb[2] + sh.fintb[3]
                            + I0 * t0s;
            out[0] = -(ll - tot);
        }
    }
}

extern "C" void kernel_launch(void* const* d_in, const int* in_sizes, int n_in,
                              void* d_out, int out_size, void* d_ws, size_t ws_size,
                              hipStream_t stream) {
    const float* times    = (const float*)d_in[0];
    const int*   types    = (const int*)  d_in[1];
    const int*   cats     = (const int*)  d_in[2];
    const int*   Tp       = (const int*)  d_in[3];
    const float* type_emb = (const float*)d_in[4];
    const float* cat_emb  = (const float*)d_in[5];
    const float* amat     = (const float*)d_in[6];
    const float* bmat     = (const float*)d_in[7];
    const float* A        = (const float*)d_in[8];
    const float* P        = (const float*)d_in[9];
    const float* Bm       = (const float*)d_in[10];
    const float* Q        = (const float*)d_in[11];
    float* out = (float*)d_out;
    float* ws  = (float*)d_ws;

    // Only the completion counter needs a known initial value (4 bytes).
    hipMemsetAsync(ws + WS_CNT, 0, sizeof(unsigned int), stream);

    hawkes_main<<<MAIN_BLOCKS, NTHREADS, 0, stream>>>(times, types, cats, Tp,
                                                      type_emb, cat_emb, amat, bmat,
                                                      A, P, Bm, Q, ws, out);
}

// Round 5
// 102.609 us; speedup vs baseline: 1.0669x; 1.0669x over previous
//
#include <hip/hip_runtime.h>

#define NTY 50
#define NCA 20
#define ED  64
#define NB  4
#define SL  256

#define LL_BLOCKS (NB * SL)            // 1024: one per (batch, event)
#define IT_BLOCKS (NB * NTY)           // 200: horizon type channel (b,t)
#define IC_BLOCKS NB                   // 4: horizon cat channel (b)
#define MAIN_BLOCKS (LL_BLOCKS + IT_BLOCKS + IC_BLOCKS)

// ws float layout — every slot has exactly ONE writer, no zero-init needed:
#define WS_L  0                        // [NB][SL]  lambda per event (i=0 incl.)
#define WS_IT (NB * SL)                // [NB][NTY] horizon type partial
#define WS_NT (NB * SL + NB * NTY)     // [NB][ED]  horizon cat n-vector

__device__ __forceinline__ float softplusf(float x) {
    return (x > 0.f) ? x + log1pf(__expf(-x)) : log1pf(__expf(x));
}

__device__ __forceinline__ float waveReduceSum(float v) {
    #pragma unroll
    for (int off = 32; off > 0; off >>= 1) v += __shfl_down(v, off, 64);
    return v;
}

struct SB {
    float2 car[NTY * ED];   // {C,R} type channel: C=te*A*f, R=te*P*f  (25.6 KB)
    float2 cbr[NCA * ED];   // {C,R} cat channel:  C=ce*Bm*g, R=ce*Q*g (10.2 KB)
    float  tsh[SL];
    int    ysh[SL];
    int    csh[SL];
    float  red[4][ED];
};

// Round-0-proven shape (high TLP, tight per-wave source loop), with the
// per-(event,source) global row gathers replaced by one-time LDS staging of
// precomputed {C,R} tables: inner loop = 2x ds_read_b64 + 2x exp per source.
__global__ __launch_bounds__(256) void hawkes_main(
        const float* __restrict__ times,
        const int*   __restrict__ types,
        const int*   __restrict__ cats,
        const int*   __restrict__ Tp,
        const float* __restrict__ type_emb,
        const float* __restrict__ cat_emb,
        const float* __restrict__ amat,
        const float* __restrict__ bmat,
        const float* __restrict__ A,
        const float* __restrict__ P,
        const float* __restrict__ Bm,
        const float* __restrict__ Q,
        float* __restrict__ ws) {
    const int blk  = blockIdx.x;
    const int tid  = threadIdx.x;
    const int lane = tid & 63;
    const int w    = tid >> 6;
    __shared__ SB sh;

    const float Tf = (float)Tp[0];

    if (blk < LL_BLOCKS) {
        // ---- lambda at event i, both channels, one block ----
        const int b = blk >> 8, i = blk & (SL - 1);
        const int base = b * SL;
        if (i == 0) {
            // empty history: lambda_0 = sum_e softplus(te[t0]*a[t0])
            if (w == 0) {
                const int t0 = types[base];
                const float lam = waveReduceSum(
                    softplusf(type_emb[t0 * ED + lane] * amat[t0 * ED + lane]));
                if (lane == 0) ws[WS_L + b * SL] = lam;
            }
            return;
        }
        const int   ti   = types[base + i];
        const int   ci   = cats[base + i - 1];
        const float tnow = times[base + i];

        if (tid < SL) {
            sh.tsh[tid] = times[base + tid];
            sh.ysh[tid] = types[base + tid];
            sh.csh[tid] = cats[base + tid];
        }
        for (int idx = tid; idx < NTY * ED; idx += 256) {
            const int e = idx & 63, k = idx >> 6;
            const float te = type_emb[ti * ED + e];
            const float f  = type_emb[idx];
            sh.car[idx] = make_float2(te * A[(k * NTY + ti) * ED + e] * f,
                                      te * P[(k * NTY + ti) * ED + e] * f);
        }
        for (int idx = tid; idx < NCA * ED; idx += 256) {
            const int e = idx & 63, k = idx >> 6;
            const float ce = cat_emb[ci * ED + e];
            const float g  = cat_emb[idx];
            sh.cbr[idx] = make_float2(ce * Bm[(k * NCA + ci) * ED + e] * g,
                                      ce * Q [(k * NCA + ci) * ED + e] * g);
        }
        __syncthreads();

        float acc = 0.f;
        #pragma unroll 4
        for (int s = w; s < i; s += 4) {
            const float  td = tnow - sh.tsh[s];
            const float2 ar = sh.car[sh.ysh[s] * ED + lane];
            const float2 bq = sh.cbr[sh.csh[s] * ED + lane];
            acc += ar.x * __expf(-ar.y * td) + bq.x * __expf(-bq.y * td);
        }
        sh.red[w][lane] = acc;
        __syncthreads();
        if (w == 0) {
            float v = sh.red[0][lane] + sh.red[1][lane]
                    + sh.red[2][lane] + sh.red[3][lane];
            v += type_emb[ti * ED + lane] * (amat[ti * ED + lane] + bmat[ci * ED + lane]);
            const float lam = waveReduceSum(v);
            if (lane == 0) ws[WS_L + b * SL + i] = lam;
        }
    } else if (blk < LL_BLOCKS + IT_BLOCKS) {
        // ---- horizon integral, type channel, (b,t) ----
        const int idx0 = blk - LL_BLOCKS;
        const int b = idx0 / NTY, t = idx0 % NTY;
        const int base = b * SL;

        if (tid < SL) {
            sh.tsh[tid] = times[base + tid];
            sh.ysh[tid] = types[base + tid];
        }
        for (int idx = tid; idx < NTY * ED; idx += 256) {
            const int e = idx & 63, k = idx >> 6;
            const float te = type_emb[t * ED + e];
            const float f  = type_emb[idx];
            sh.car[idx] = make_float2(te * A[(k * NTY + t) * ED + e] * f,
                                      te * P[(k * NTY + t) * ED + e] * f);
        }
        __syncthreads();

        float acc = 0.f;
        #pragma unroll 4
        for (int s = w; s < SL; s += 4) {
            const float  td = Tf - sh.tsh[s];
            const float2 ar = sh.car[sh.ysh[s] * ED + lane];
            acc += ar.x * __expf(-ar.y * td);
        }
        sh.red[w][lane] = acc;
        __syncthreads();
        if (w == 0) {
            float v = sh.red[0][lane] + sh.red[1][lane]
                    + sh.red[2][lane] + sh.red[3][lane];
            v += type_emb[t * ED + lane] * amat[t * ED + lane];
            const float r = waveReduceSum(v);
            if (lane == 0) ws[WS_IT + b * NTY + t] = r;
        }
    } else {
        // ---- horizon integral, cat channel n-vector, per b ----
        const int b = blk - LL_BLOCKS - IT_BLOCKS;
        const int base = b * SL;
        const int lc = cats[base + SL - 1];

        if (tid < SL) {
            sh.tsh[tid] = times[base + tid];
            sh.csh[tid] = cats[base + tid];
        }
        for (int idx = tid; idx < NCA * ED; idx += 256) {
            const int e = idx & 63, k = idx >> 6;
            const float ce = cat_emb[lc * ED + e];
            const float g  = cat_emb[idx];
            sh.cbr[idx] = make_float2(ce * Bm[(k * NCA + lc) * ED + e] * g,
                                      ce * Q [(k * NCA + lc) * ED + e] * g);
        }
        __syncthreads();

        float acc = 0.f;
        #pragma unroll 4
        for (int s = w; s < SL; s += 4) {
            const float  td = Tf - sh.tsh[s];
            const float2 bq = sh.cbr[sh.csh[s] * ED + lane];
            acc += bq.x * __expf(-bq.y * td);
        }
        sh.red[w][lane] = acc;
        __syncthreads();
        if (w == 0)
            ws[WS_NT + b * ED + lane] = sh.red[0][lane] + sh.red[1][lane]
                                      + sh.red[2][lane] + sh.red[3][lane];
    }
}

__global__ __launch_bounds__(256) void hawkes_final(
        const float* __restrict__ times,
        const int*   __restrict__ cats,
        const int*   __restrict__ Tp,
        const float* __restrict__ type_emb,
        const float* __restrict__ amat,
        const float* __restrict__ bmat,
        const float* __restrict__ ws,
        float* __restrict__ out) {
    const int tid  = threadIdx.x;
    const int lane = tid & 63;
    const int w    = tid >> 6;          // wave w also owns batch w

    __shared__ float tsl[4][ED];
    __shared__ float wred[4], i0red[4], intb[4];

    const float Tf = (float)Tp[0];

    // ---- log-likelihood: thread tid -> event i=tid, all batches ----
    float llp = 0.f;
    {
        #pragma unroll
        for (int bb = 0; bb < NB; ++bb) {
            const float lam = ws[WS_L + bb * SL + tid];
            llp += logf(lam + 1e-16f) + lam;
        }
    }

    // ---- TS[e] = sum_t te[t,e] and I0 = sum softplus(te*a), t split by wave ----
    float tsp = 0.f, i0p = 0.f;
    for (int t = w; t < NTY; t += 4) {
        const float tv = type_emb[t * ED + lane];
        tsp += tv;
        i0p += softplusf(tv * amat[t * ED + lane]);
    }
    tsl[w][lane] = tsp;

    const float wll = waveReduceSum(llp);
    const float wi0 = waveReduceSum(i0p);
    if (lane == 0) {
        wred[w]  = wll;
        i0red[w] = wi0;
    }
    __syncthreads();

    // ---- horizon integral for batch w ----
    const float TS_l = tsl[0][lane] + tsl[1][lane] + tsl[2][lane] + tsl[3][lane];
    const int   lc   = cats[w * SL + SL - 1];
    const float bbv  = bmat[lc * ED + lane] + ws[WS_NT + w * ED + lane];
    const float its  = (lane < NTY) ? ws[WS_IT + w * NTY + lane] : 0.f;
    const float ip   = waveReduceSum(its + bbv * TS_l);
    if (lane == 0) intb[w] = ip * (Tf - times[w * SL + SL - 1]);
    __syncthreads();

    if (tid == 0) {
        const float ll  = wred[0] + wred[1] + wred[2] + wred[3];
        const float I0  = i0red[0] + i0red[1] + i0red[2] + i0red[3];
        const float t0s = times[0] + times[SL] + times[2 * SL] + times[3 * SL];
        const float tot = intb[0] + intb[1] + intb[2] + intb[3] + I0 * t0s;
        out[0] = -(ll - tot);
    }
}

extern "C" void kernel_launch(void* const* d_in, const int* in_sizes, int n_in,
                              void* d_out, int out_size, void* d_ws, size_t ws_size,
                              hipStream_t stream) {
    const float* times    = (const float*)d_in[0];
    const int*   types    = (const int*)  d_in[1];
    const int*   cats     = (const int*)  d_in[2];
    const int*   Tp       = (const int*)  d_in[3];
    const float* type_emb = (const float*)d_in[4];
    const float* cat_emb  = (const float*)d_in[5];
    const float* amat     = (const float*)d_in[6];
    const float* bmat     = (const float*)d_in[7];
    const float* A        = (const float*)d_in[8];
    const float* P        = (const float*)d_in[9];
    const float* Bm       = (const float*)d_in[10];
    const float* Q        = (const float*)d_in[11];
    float* out = (float*)d_out;
    float* ws  = (float*)d_ws;

    // No memset: every ws slot read by hawkes_final is written exactly once.
    hawkes_main<<<MAIN_BLOCKS, 256, 0, stream>>>(times, types, cats, Tp,
                                                 type_emb, cat_emb, amat, bmat,
                                                 A, P, Bm, Q, ws);
    hawkes_final<<<1, 256, 0, stream>>>(times, cats, Tp,
                                        type_emb, amat, bmat, ws, out);
}